// Round 2
// baseline (384.436 us; speedup 1.0000x reference)
//
#include <hip/hip_runtime.h>
#include <hip/hip_bf16.h>

// x: (2,40,40,40,64) f32 -> out: same shape f32 = conv3d(x, K), sc folded into
// center tap. ws: xp bf16 padded (2,44,44,44,64) @0, Kb bf16 [125][8][64][8] @XP_BYTES.
// Kb total = 1 MB -> L2-resident; conv reads B straight from global (no LDS, no barriers).

typedef __bf16 bf16x8 __attribute__((ext_vector_type(8)));
typedef float f32x4 __attribute__((ext_vector_type(4)));

#define XP_BYTES 21807104

// ---------------- pad + cast x -> xp (zero borders, bf16) ----------------
__global__ __launch_bounds__(256) void pad_cast(const float* __restrict__ x,
                                                ushort* __restrict__ xp) {
  int tid = blockIdx.x * 256 + threadIdx.x;      // 0 .. 1,362,943
  int c8 = (tid & 7) * 8;                        // channel chunk of 8
  int v = tid >> 3;                              // voxel id in padded grid
  int zi = v % 44; int t = v / 44;
  int yi = t % 44; t /= 44;
  int xi = t % 44; int n = t / 44;
  int4 st;
  if (xi >= 2 && xi < 42 && yi >= 2 && yi < 42 && zi >= 2 && zi < 42) {
    const float* src = x + ((((size_t)n * 40 + (xi - 2)) * 40 + (yi - 2)) * 40 + (zi - 2)) * 64 + c8;
    float4 f0 = ((const float4*)src)[0];
    float4 f1 = ((const float4*)src)[1];
    union { __hip_bfloat16 h[8]; int4 v4; } u;
    u.h[0] = __float2bfloat16(f0.x); u.h[1] = __float2bfloat16(f0.y);
    u.h[2] = __float2bfloat16(f0.z); u.h[3] = __float2bfloat16(f0.w);
    u.h[4] = __float2bfloat16(f1.x); u.h[5] = __float2bfloat16(f1.y);
    u.h[6] = __float2bfloat16(f1.z); u.h[7] = __float2bfloat16(f1.w);
    st = u.v4;
  } else {
    st = make_int4(0, 0, 0, 0);
  }
  ((int4*)xp)[tid] = st;
}

// ---------------- build Kb: one thread per element, coalesced ----------------
// Kb flat index = ((l*8 + (i>>3))*64 + o)*8 + (i&7)
__global__ __launch_bounds__(256) void build_k(const float* __restrict__ lw,
                                               const float* __restrict__ wt,
                                               ushort* __restrict__ Kb) {
  int tid = blockIdx.x * 256 + threadIdx.x;   // 0 .. 511,999
  int j  = tid & 7;
  int o  = (tid >> 3) & 63;
  int kg = (tid >> 9) & 7;
  int l  = tid >> 12;
  int i  = kg * 8 + j;

  int ix = l / 25; int rem = l - ix * 25; int iy = rem / 5; int iz = rem - iy * 5;
  float cx = (float)(ix - 2), cy = (float)(iy - 2), cz = (float)(iz - 2);
  float r = sqrtf(cx * cx + cy * cy + cz * cz);

  float e[8];
  const float step = 2.5f / 9.0f;
  #pragma unroll
  for (int b = 0; b < 8; b++) {
    float diff = (r - (float)(b + 1) * step) / step;
    float den = fmaxf(1.0f - diff * diff, 1e-9f);
    e[b] = (fabsf(diff) < 1.0f) ? 1.14136f * expf(2.0f - 1.0f / den) : 0.0f;
  }
  float inv = (r > 0.0f) ? 1.0f / r : 0.0f;
  const float s3 = 1.7320508075688772f;
  float y1[3] = { s3 * cx * inv, s3 * cy * inv, s3 * cz * inv };
  const float a  = 0.17677669529663687f;     // 1/sqrt(2*MUL)
  const float a3 = 0.10206207261596575f;     // a/sqrt(3)

  auto wElem = [&](int c, int u, int w) -> float {
    const float* p = wt + c * 256 + u * 16 + w;
    float s = 0.f;
    #pragma unroll
    for (int b = 0; b < 8; b++) s += e[b] * p[b * 1024];
    return s * (1.0f / 125.0f);
  };

  float val;
  if (i < 16) {
    if (o < 16) {                       // Rss
      val = a * wElem(0, i, o);
    } else {                            // Rsv
      int om = o - 16; int w = om / 3, m = om - 3 * w;
      val = a * wElem(1, i, w) * y1[m];
    }
  } else {
    int im = i - 16; int u = im / 3, m = im - 3 * u;
    if (o < 16) {                       // Rvs
      val = a3 * wElem(3, u, o) * y1[m];
    } else {                            // Rvv (diagonal in m,n)
      int om = o - 16; int w = om / 3, n = om - 3 * w;
      val = (m == n) ? a * wElem(2, u, w) : 0.0f;
    }
  }
  // fold self-connection into center tap (2,2,2) -> l == 62
  if (l == 62) {
    if (i < 16 && o < 16) {
      val += lw[i * 16 + o] * 0.25f;
    } else if (i >= 16 && o >= 16) {
      int im = i - 16, om = o - 16;
      int u = im / 3, m = im - 3 * u;
      int w = om / 3, n = om - 3 * w;
      if (m == n) val += lw[256 + u * 16 + w] * 0.25f;
    }
  }
  __hip_bfloat16 h = __float2bfloat16(val);
  Kb[tid] = *(ushort*)&h;
}

// ---------------- conv: barrier-free implicit GEMM ----------------
// block = 4 waves, each wave: M=64 (4 m-tiles of 16 rows) x N=64, K=8000.
// A from global (padded xp, L1-reused across dz taps), B from global (Kb 1MB,
// L2-resident; per-tap 8KB slice L1-resident, shared by all waves).
__global__ __launch_bounds__(256, 3) void conv_mfma(const ushort* __restrict__ xp_,
                                                    const ushort* __restrict__ Kb_,
                                                    float* __restrict__ out) {
  const __bf16* xp = (const __bf16*)xp_;
  const __bf16* Kb = (const __bf16*)Kb_;

  const int lane = threadIdx.x & 63;
  const int wv = threadIdx.x >> 6;
  const int g = lane >> 4;         // k-group (and acc row-group)
  const int ol = lane & 15;        // row within m-tile (A) / col (B, C)
  const int pw = blockIdx.x * 256 + wv * 64;   // wave's first position

  // per-lane A-row base offsets for the 4 m-tiles
  size_t baseOff[4];
  #pragma unroll
  for (int mt = 0; mt < 4; mt++) {
    int p = pw + mt * 16 + ol;
    int z = p % 40; int q = p / 40;
    int y = q % 40; q /= 40;
    int x = q % 40; int n = q / 40;
    baseOff[mt] = ((((size_t)n * 44 + x) * 44 + y) * 44 + z) * 64 + g * 8;
  }

  f32x4 acc[4][4] = {};  // [mt][nt]

  for (int l = 0; l < 125; l++) {
    int dx = l / 25; int rem = l - dx * 25; int dy = rem / 5; int dz = rem - dy * 5;
    size_t tapOff = ((size_t)(dx * 44 + dy) * 44 + dz) * 64;

    bf16x8 a[4][2], b[2][4];
    #pragma unroll
    for (int mt = 0; mt < 4; mt++)
      #pragma unroll
      for (int kc = 0; kc < 2; kc++)
        a[mt][kc] = *(const bf16x8*)(xp + baseOff[mt] + tapOff + kc * 32);

    const __bf16* kb = Kb + (size_t)l * 4096 + (g * 64 + ol) * 8;
    #pragma unroll
    for (int kc = 0; kc < 2; kc++)
      #pragma unroll
      for (int nt = 0; nt < 4; nt++)
        b[kc][nt] = *(const bf16x8*)(kb + (kc * 4 * 64 + nt * 16) * 8);

    #pragma unroll
    for (int kc = 0; kc < 2; kc++)
      #pragma unroll
      for (int nt = 0; nt < 4; nt++)
        #pragma unroll
        for (int mt = 0; mt < 4; mt++)
          acc[mt][nt] = __builtin_amdgcn_mfma_f32_16x16x32_bf16(a[mt][kc], b[kc][nt], acc[mt][nt], 0, 0, 0);
  }

  // epilogue: C/D layout col=lane&15, row=(lane>>4)*4+j
  #pragma unroll
  for (int mt = 0; mt < 4; mt++) {
    #pragma unroll
    for (int nt = 0; nt < 4; nt++) {
      #pragma unroll
      for (int j = 0; j < 4; j++) {
        int p = pw + mt * 16 + g * 4 + j;
        out[(size_t)p * 64 + nt * 16 + ol] = acc[mt][nt][j];
      }
    }
  }
}

extern "C" void kernel_launch(void* const* d_in, const int* in_sizes, int n_in,
                              void* d_out, int out_size, void* d_ws, size_t ws_size,
                              hipStream_t stream) {
  const float* x  = (const float*)d_in[0];
  const float* lw = (const float*)d_in[1];
  const float* wt = (const float*)d_in[2];
  float* out = (float*)d_out;
  ushort* xp = (ushort*)d_ws;
  ushort* Kb = (ushort*)((char*)d_ws + XP_BYTES);

  pad_cast<<<5324, 256, 0, stream>>>(x, xp);
  build_k<<<2000, 256, 0, stream>>>(lw, wt, Kb);
  conv_mfma<<<500, 256, 0, stream>>>(xp, Kb, out);
}

// Round 3
// 256.550 us; speedup vs baseline: 1.4985x; 1.4985x over previous
//
#include <hip/hip_runtime.h>
#include <hip/hip_bf16.h>

// out(2,40,40,40,64) f32 = conv3d(x, K), self-connection folded into center tap.
// ws: xp bf16 padded (2,44,44,44,64) @0, Kb bf16 [125][8][64][8] @XP_BYTES.
// conv: block = 160 positions (4 y-cols x 40 z, one x-plane), 4 waves 2Mx2N.
// Per dx-group: stage 8 y-col slab into LDS transposed [ch-chunk][row] so all
// 25 (dy,dz) taps read A via ds_read_b128 with pure immediate offsets.

typedef __bf16 bf16x8 __attribute__((ext_vector_type(8)));
typedef float f32x4 __attribute__((ext_vector_type(4)));

#define XP_BYTES 21807104
#define COLSTRIDE 6160      // bytes per ch-chunk column: 385 chunks * 16B (pad vs 352 for bank spread)
#define LDS_BYTES 49280     // 8 * COLSTRIDE

// ---------------- prep: pad_cast (blocks 0..5323) + build_k (blocks 5324..7323) ----------------
__global__ __launch_bounds__(256) void prep(const float* __restrict__ x,
                                            const float* __restrict__ lw,
                                            const float* __restrict__ wt,
                                            ushort* __restrict__ xp,
                                            ushort* __restrict__ Kb) {
  if (blockIdx.x < 5324) {
    int tid = blockIdx.x * 256 + threadIdx.x;      // 0 .. 1,362,943
    int c8 = (tid & 7) * 8;
    int v = tid >> 3;
    int zi = v % 44; int t = v / 44;
    int yi = t % 44; t /= 44;
    int xi = t % 44; int n = t / 44;
    int4 st;
    if (xi >= 2 && xi < 42 && yi >= 2 && yi < 42 && zi >= 2 && zi < 42) {
      const float* src = x + ((((size_t)n * 40 + (xi - 2)) * 40 + (yi - 2)) * 40 + (zi - 2)) * 64 + c8;
      float4 f0 = ((const float4*)src)[0];
      float4 f1 = ((const float4*)src)[1];
      union { __hip_bfloat16 h[8]; int4 v4; } u;
      u.h[0] = __float2bfloat16(f0.x); u.h[1] = __float2bfloat16(f0.y);
      u.h[2] = __float2bfloat16(f0.z); u.h[3] = __float2bfloat16(f0.w);
      u.h[4] = __float2bfloat16(f1.x); u.h[5] = __float2bfloat16(f1.y);
      u.h[6] = __float2bfloat16(f1.z); u.h[7] = __float2bfloat16(f1.w);
      st = u.v4;
    } else {
      st = make_int4(0, 0, 0, 0);
    }
    ((int4*)xp)[tid] = st;
  } else {
    int tid = (blockIdx.x - 5324) * 256 + threadIdx.x;   // 0 .. 511,999
    int j  = tid & 7;
    int o  = (tid >> 3) & 63;
    int kg = (tid >> 9) & 7;
    int l  = tid >> 12;
    int i  = kg * 8 + j;

    int ix = l / 25; int rem = l - ix * 25; int iy = rem / 5; int iz = rem - iy * 5;
    float cx = (float)(ix - 2), cy = (float)(iy - 2), cz = (float)(iz - 2);
    float r = sqrtf(cx * cx + cy * cy + cz * cz);

    float e[8];
    const float step = 2.5f / 9.0f;
    #pragma unroll
    for (int b = 0; b < 8; b++) {
      float diff = (r - (float)(b + 1) * step) / step;
      float den = fmaxf(1.0f - diff * diff, 1e-9f);
      e[b] = (fabsf(diff) < 1.0f) ? 1.14136f * expf(2.0f - 1.0f / den) : 0.0f;
    }
    float inv = (r > 0.0f) ? 1.0f / r : 0.0f;
    const float s3 = 1.7320508075688772f;
    float y1[3] = { s3 * cx * inv, s3 * cy * inv, s3 * cz * inv };
    const float a  = 0.17677669529663687f;     // 1/sqrt(2*MUL)
    const float a3 = 0.10206207261596575f;     // a/sqrt(3)

    auto wElem = [&](int c, int u, int w) -> float {
      const float* p = wt + c * 256 + u * 16 + w;
      float s = 0.f;
      #pragma unroll
      for (int b = 0; b < 8; b++) s += e[b] * p[b * 1024];
      return s * (1.0f / 125.0f);
    };

    float val;
    if (i < 16) {
      if (o < 16) {                       // Rss
        val = a * wElem(0, i, o);
      } else {                            // Rsv
        int om = o - 16; int w = om / 3, m = om - 3 * w;
        val = a * wElem(1, i, w) * y1[m];
      }
    } else {
      int im = i - 16; int u = im / 3, m = im - 3 * u;
      if (o < 16) {                       // Rvs
        val = a3 * wElem(3, u, o) * y1[m];
      } else {                            // Rvv (diagonal in m,n)
        int om = o - 16; int w = om / 3, nn = om - 3 * w;
        val = (m == nn) ? a * wElem(2, u, w) : 0.0f;
      }
    }
    if (l == 62) {   // center tap: fold self-connection
      if (i < 16 && o < 16) {
        val += lw[i * 16 + o] * 0.25f;
      } else if (i >= 16 && o >= 16) {
        int im = i - 16, om = o - 16;
        int u = im / 3, m = im - 3 * u;
        int w = om / 3, nn = om - 3 * w;
        if (m == nn) val += lw[256 + u * 16 + w] * 0.25f;
      }
    }
    __hip_bfloat16 h = __float2bfloat16(val);
    Kb[tid] = *(ushort*)&h;
  }
}

// ---------------- conv ----------------
__global__ __launch_bounds__(256, 3) void conv_mfma(const ushort* __restrict__ xp_,
                                                    const ushort* __restrict__ Kb_,
                                                    float* __restrict__ out) {
  const char* xpB = (const char*)xp_;
  const char* KbB = (const char*)Kb_;
  __shared__ __align__(16) char smem[LDS_BYTES];

  const int tid = threadIdx.x;
  const int lane = tid & 63;
  const int wv = tid >> 6;
  const int wm = wv & 1, wn = wv >> 1;
  const int g = lane >> 4, ol = lane & 15;

  int bid = blockIdx.x;                    // 800 blocks = 2n x 40x x 10yg
  int yg = bid % 10; int t = bid / 10;
  int xx = t % 40; int n = t / 40;
  int y0 = yg * 4;
  int p0 = ((n * 40 + xx) * 40 + y0) * 40;

  // per-lane LDS byte base per m-tile (row = yrel*44 + z, col = g; kc/tap in immediates)
  int lanebase[5];
  #pragma unroll
  for (int mt = 0; mt < 5; mt++) {
    int r = wm * 80 + mt * 16 + ol;
    int yrel = r / 40, z = r - yrel * 40;
    lanebase[mt] = g * COLSTRIDE + (yrel * 44 + z) * 16;
  }

  // B per-lane byte base within a tap slice (8192 B per tap)
  const int bbase = g * 1024 + wn * 512 + ol * 16;

  f32x4 acc[5][2] = {};

  const size_t slab0 = ((((size_t)n * 44 + xx) * 44 + y0) * 44) * 128;  // bytes at (n, xx, y0, z=0, ch=0)

  for (int dx = 0; dx < 5; dx++) {
    const char* slab = xpB + slab0 + (size_t)dx * (44 * 44 * 128);
    int4 v[6];
    // batch A loads (independent of LDS) before the barrier
    #pragma unroll
    for (int it = 0; it < 6; it++)
      v[it] = *(const int4*)(slab + ((size_t)(it * 256 + tid)) * 16);
    if (dx > 0) __syncthreads();           // prior tap reads done before overwrite
    #pragma unroll
    for (int it = 0; it < 6; it++) {
      int c = it * 256 + tid;
      *(int4*)(smem + (c & 7) * COLSTRIDE + (c >> 3) * 16) = v[it];
    }
    #pragma unroll
    for (int it = 0; it < 5; it++)
      v[it] = *(const int4*)(slab + ((size_t)((it + 6) * 256 + tid)) * 16);
    #pragma unroll
    for (int it = 0; it < 5; it++) {
      int c = (it + 6) * 256 + tid;
      *(int4*)(smem + (c & 7) * COLSTRIDE + (c >> 3) * 16) = v[it];
    }
    __syncthreads();

    const char* kbdx = KbB + (size_t)dx * 25 * 8192 + bbase;
    #pragma unroll
    for (int dy = 0; dy < 5; dy++) {
      #pragma unroll
      for (int dz = 0; dz < 5; dz++) {
        const int toff = (dy * 44 + dz) * 16;
        bf16x8 a[5][2], b[2][2];
        #pragma unroll
        for (int mt = 0; mt < 5; mt++)
          #pragma unroll
          for (int kc = 0; kc < 2; kc++)
            a[mt][kc] = *(const bf16x8*)(smem + lanebase[mt] + kc * (4 * COLSTRIDE) + toff);
        const char* kb = kbdx + (dy * 5 + dz) * 8192;
        #pragma unroll
        for (int kc = 0; kc < 2; kc++)
          #pragma unroll
          for (int nt = 0; nt < 2; nt++)
            b[kc][nt] = *(const bf16x8*)(kb + kc * 4096 + nt * 256);
        #pragma unroll
        for (int kc = 0; kc < 2; kc++)
          #pragma unroll
          for (int nt = 0; nt < 2; nt++)
            #pragma unroll
            for (int mt = 0; mt < 5; mt++)
              acc[mt][nt] = __builtin_amdgcn_mfma_f32_16x16x32_bf16(a[mt][kc], b[kc][nt], acc[mt][nt], 0, 0, 0);
      }
    }
  }

  // epilogue: C/D col = ol, row = g*4 + j
  #pragma unroll
  for (int mt = 0; mt < 5; mt++)
    #pragma unroll
    for (int nt = 0; nt < 2; nt++)
      #pragma unroll
      for (int j = 0; j < 4; j++) {
        int p = p0 + wm * 80 + mt * 16 + g * 4 + j;
        out[(size_t)p * 64 + wn * 32 + nt * 16 + ol] = acc[mt][nt][j];
      }
}

extern "C" void kernel_launch(void* const* d_in, const int* in_sizes, int n_in,
                              void* d_out, int out_size, void* d_ws, size_t ws_size,
                              hipStream_t stream) {
  const float* x  = (const float*)d_in[0];
  const float* lw = (const float*)d_in[1];
  const float* wt = (const float*)d_in[2];
  float* out = (float*)d_out;
  ushort* xp = (ushort*)d_ws;
  ushort* Kb = (ushort*)((char*)d_ws + XP_BYTES);

  prep<<<7324, 256, 0, stream>>>(x, lw, wt, xp, Kb);
  conv_mfma<<<800, 256, 0, stream>>>(xp, Kb, out);
}